// Round 11
// baseline (81.112 us; speedup 1.0000x reference)
//
#include <hip/hip_runtime.h>
#include <math.h>

#define N 768
#define CS 384
#define CP 128
#define NBIN 65
#define KH (CS / 2)  // 192: K-split half

typedef float f4 __attribute__((ext_vector_type(4)));
typedef float f2 __attribute__((ext_vector_type(2)));

#define PROJ_BLOCKS (N / 4)            // 192 (4 rows each)
#define REL_BLOCKS ((NBIN + 3) / 4)    // 17 (4 bins each)

// Prep (R9 known-good): 512-thread blocks, K-split halves, LDS combine.
__global__ __launch_bounds__(512) void prep_kernel(
    const float* __restrict__ s,
    const float* __restrict__ Wi, const float* __restrict__ bi,
    const float* __restrict__ Wj, const float* __restrict__ bj,
    const float* __restrict__ Wrel, const float* __restrict__ brel,
    const float* __restrict__ bt,
    float* __restrict__ pI, float* __restrict__ pJ, float* __restrict__ relT) {
  const int tid = threadIdx.x;

  if (blockIdx.x >= PROJ_BLOCKS) {
    const int bb = (blockIdx.x - PROJ_BLOCKS) * 4 + (tid >> 7);
    const int p = tid & 127;
    if (bb < NBIN)
      relT[bb * CP + p] = Wrel[p * NBIN + bb] + brel[p] + bt[p];
    return;
  }

  __shared__ float s_sh[4 * CS];                 // 6 KB
  __shared__ float part_sh[2][2][128][4];        // 8 KB: [which][kh][p][row]

  const int n0 = blockIdx.x * 4;
  if (tid < 4 * CS / 4)
    reinterpret_cast<f4*>(s_sh)[tid] = reinterpret_cast<const f4*>(s + n0 * CS)[tid];
  __syncthreads();

  const int which = tid >> 8;        // 0 -> i, 1 -> j
  const int kh = (tid >> 7) & 1;     // K half
  const int p = tid & 127;
  const float* W = which ? Wj : Wi;
  const f4* W4 = reinterpret_cast<const f4*>(W + p * CS + kh * KH);
  const f4* S4 = reinterpret_cast<const f4*>(s_sh + kh * KH);

  float acc0 = 0.f, acc1 = 0.f, acc2 = 0.f, acc3 = 0.f;
#pragma unroll 8
  for (int c4 = 0; c4 < KH / 4; ++c4) {
    const f4 w = W4[c4];
    const f4 s0 = S4[0 * (CS / 4) + c4];
    const f4 s1 = S4[1 * (CS / 4) + c4];
    const f4 s2 = S4[2 * (CS / 4) + c4];
    const f4 s3 = S4[3 * (CS / 4) + c4];
    acc0 += s0.x * w.x + s0.y * w.y + s0.z * w.z + s0.w * w.w;
    acc1 += s1.x * w.x + s1.y * w.y + s1.z * w.z + s1.w * w.w;
    acc2 += s2.x * w.x + s2.y * w.y + s2.z * w.z + s2.w * w.w;
    acc3 += s3.x * w.x + s3.y * w.y + s3.z * w.z + s3.w * w.w;
  }
  part_sh[which][kh][p][0] = acc0;
  part_sh[which][kh][p][1] = acc1;
  part_sh[which][kh][p][2] = acc2;
  part_sh[which][kh][p][3] = acc3;
  __syncthreads();

  if (tid < 256) {
    const int w2 = tid >> 7;
    const int p2 = tid & 127;
    const float b = w2 ? bj[p2] : bi[p2];
    float* outp = w2 ? pJ : pI;
#pragma unroll
    for (int r = 0; r < 4; ++r)
      outp[(n0 + r) * CP + p2] =
          part_sh[w2][0][p2][r] + part_sh[w2][1][p2][r] + b;
  }
}

// Pair kernel, row-sweep + nt stores + hoisted rel.
// One block per n-row; 92% of iterations: 1 L2 load (pj) + 1 LDS broadcast
// per 16B nontemporal store (no L2/MALL allocation for the 302MB stream).
__global__ __launch_bounds__(256) void pair_kernel(
    const float* __restrict__ pI, const float* __restrict__ pJ,
    const float* __restrict__ relT, const float* __restrict__ Wt,
    const float* __restrict__ trans, const float* __restrict__ mask,
    float* __restrict__ out) {
  __shared__ f2 dm_sh[N];   // {dist, mask} for the whole row: 6 KB

  const int n = blockIdx.x;
  const int tid = threadIdx.x;

  const float tx = trans[n * 3 + 0];
  const float ty = trans[n * 3 + 1];
  const float tz = trans[n * 3 + 2];
  for (int m = tid; m < N; m += 256) {
    const float dx = tx - trans[m * 3 + 0];
    const float dy = ty - trans[m * 3 + 1];
    const float dz = tz - trans[m * 3 + 2];
    f2 dm;
    dm.x = sqrtf(1e-10f + dx * dx + dy * dy + dz * dz);
    dm.y = mask[n * N + m];
    dm_sh[m] = dm;
  }
  __syncthreads();

  const int v = tid & 31;        // float4 index within 128 channels
  const int slot = tid >> 5;     // 0..7

  const f4 pi4 = reinterpret_cast<const f4*>(pI)[n * (CP / 4) + v];
  const f4 wt4 = reinterpret_cast<const f4*>(Wt)[v];
  const f4* __restrict__ pJ4 = reinterpret_cast<const f4*>(pJ);
  const f4* __restrict__ rel4 = reinterpret_cast<const f4*>(relT);
  f4* __restrict__ out4 =
      reinterpret_cast<f4*>(out) + (size_t)n * N * (CP / 4);

  // d = n - m; m <= n-32 -> bin 64, m >= n+32 -> bin 0. Hoist both into regs.
  const f4 base_lo = pi4 + rel4[64 * (CP / 4) + v];   // d >= 32
  const f4 base_hi = pi4 + rel4[0 * (CP / 4) + v];    // d <= -32

#pragma unroll 8
  for (int mm = slot; mm < N; mm += 8) {
    const int d = n - mm;
    f4 base;
    if (d >= 32) {
      base = base_lo;
    } else if (d <= -32) {
      base = base_hi;
    } else {
      base = pi4 + rel4[(d + 32) * (CP / 4) + v];
    }

    const f4 pj4 = pJ4[mm * (CP / 4) + v];
    const f2 dm = dm_sh[mm];

    const f4 o = (base + pj4 + dm.x * wt4) * dm.y;
    __builtin_nontemporal_store(o, &out4[mm * (CP / 4) + v]);
  }
}

extern "C" void kernel_launch(void* const* d_in, const int* in_sizes, int n_in,
                              void* d_out, int out_size, void* d_ws, size_t ws_size,
                              hipStream_t stream) {
  const float* s      = (const float*)d_in[0];
  const float* trans  = (const float*)d_in[1];
  const float* p_mask = (const float*)d_in[2];
  const float* Wi     = (const float*)d_in[3];
  const float* bi     = (const float*)d_in[4];
  const float* Wj     = (const float*)d_in[5];
  const float* bj     = (const float*)d_in[6];
  const float* Wrel   = (const float*)d_in[7];
  const float* brel   = (const float*)d_in[8];
  const float* Wt     = (const float*)d_in[9];
  const float* bt     = (const float*)d_in[10];
  float* out = (float*)d_out;

  float* ws   = (float*)d_ws;
  float* pI   = ws;                 // N*CP floats
  float* pJ   = ws + N * CP;        // N*CP floats
  float* relT = ws + 2 * N * CP;    // NBIN*CP floats

  prep_kernel<<<PROJ_BLOCKS + REL_BLOCKS, 512, 0, stream>>>(
      s, Wi, bi, Wj, bj, Wrel, brel, bt, pI, pJ, relT);
  pair_kernel<<<N, 256, 0, stream>>>(
      pI, pJ, relT, Wt, trans, p_mask, out);
}

// Round 12
// 69.505 us; speedup vs baseline: 1.1670x; 1.1670x over previous
//
#include <hip/hip_runtime.h>
#include <math.h>

#define N 768
#define CS 384
#define CP 128
#define NBIN 65
#define KH (CS / 2)  // 192: K-split half

typedef float f4 __attribute__((ext_vector_type(4)));
typedef float f2 __attribute__((ext_vector_type(2)));

#define PROJ_BLOCKS (N / 4)            // 192 (4 rows each)
#define REL_BLOCKS ((NBIN + 3) / 4)    // 17 (4 bins each)

// Prep (R9 known-good): 512-thread blocks, K-split halves, LDS combine.
__global__ __launch_bounds__(512) void prep_kernel(
    const float* __restrict__ s,
    const float* __restrict__ Wi, const float* __restrict__ bi,
    const float* __restrict__ Wj, const float* __restrict__ bj,
    const float* __restrict__ Wrel, const float* __restrict__ brel,
    const float* __restrict__ bt,
    float* __restrict__ pI, float* __restrict__ pJ, float* __restrict__ relT) {
  const int tid = threadIdx.x;

  if (blockIdx.x >= PROJ_BLOCKS) {
    const int bb = (blockIdx.x - PROJ_BLOCKS) * 4 + (tid >> 7);
    const int p = tid & 127;
    if (bb < NBIN)
      relT[bb * CP + p] = Wrel[p * NBIN + bb] + brel[p] + bt[p];
    return;
  }

  __shared__ float s_sh[4 * CS];                 // 6 KB
  __shared__ float part_sh[2][2][128][4];        // 8 KB: [which][kh][p][row]

  const int n0 = blockIdx.x * 4;
  if (tid < 4 * CS / 4)
    reinterpret_cast<f4*>(s_sh)[tid] = reinterpret_cast<const f4*>(s + n0 * CS)[tid];
  __syncthreads();

  const int which = tid >> 8;        // 0 -> i, 1 -> j
  const int kh = (tid >> 7) & 1;     // K half
  const int p = tid & 127;
  const float* W = which ? Wj : Wi;
  const f4* W4 = reinterpret_cast<const f4*>(W + p * CS + kh * KH);
  const f4* S4 = reinterpret_cast<const f4*>(s_sh + kh * KH);

  float acc0 = 0.f, acc1 = 0.f, acc2 = 0.f, acc3 = 0.f;
#pragma unroll 8
  for (int c4 = 0; c4 < KH / 4; ++c4) {
    const f4 w = W4[c4];
    const f4 s0 = S4[0 * (CS / 4) + c4];
    const f4 s1 = S4[1 * (CS / 4) + c4];
    const f4 s2 = S4[2 * (CS / 4) + c4];
    const f4 s3 = S4[3 * (CS / 4) + c4];
    acc0 += s0.x * w.x + s0.y * w.y + s0.z * w.z + s0.w * w.w;
    acc1 += s1.x * w.x + s1.y * w.y + s1.z * w.z + s1.w * w.w;
    acc2 += s2.x * w.x + s2.y * w.y + s2.z * w.z + s2.w * w.w;
    acc3 += s3.x * w.x + s3.y * w.y + s3.z * w.z + s3.w * w.w;
  }
  part_sh[which][kh][p][0] = acc0;
  part_sh[which][kh][p][1] = acc1;
  part_sh[which][kh][p][2] = acc2;
  part_sh[which][kh][p][3] = acc3;
  __syncthreads();

  if (tid < 256) {
    const int w2 = tid >> 7;
    const int p2 = tid & 127;
    const float b = w2 ? bj[p2] : bi[p2];
    float* outp = w2 ? pJ : pI;
#pragma unroll
    for (int r = 0; r < 4; ++r)
      outp[(n0 + r) * CP + p2] =
          part_sh[w2][0][p2][r] + part_sh[w2][1][p2][r] + b;
  }
}

// Pair kernel, row-sweep (R10) + hoisted rel, PLAIN stores.
// One block per n-row; off-band iterations (92%) do 1 L2 load + 1 LDS read
// per 16B store.
__global__ __launch_bounds__(256) void pair_kernel(
    const float* __restrict__ pI, const float* __restrict__ pJ,
    const float* __restrict__ relT, const float* __restrict__ Wt,
    const float* __restrict__ trans, const float* __restrict__ mask,
    float* __restrict__ out) {
  __shared__ f2 dm_sh[N];   // {dist, mask} for the whole row: 6 KB

  const int n = blockIdx.x;
  const int tid = threadIdx.x;

  const float tx = trans[n * 3 + 0];
  const float ty = trans[n * 3 + 1];
  const float tz = trans[n * 3 + 2];
  for (int m = tid; m < N; m += 256) {
    const float dx = tx - trans[m * 3 + 0];
    const float dy = ty - trans[m * 3 + 1];
    const float dz = tz - trans[m * 3 + 2];
    f2 dm;
    dm.x = sqrtf(1e-10f + dx * dx + dy * dy + dz * dz);
    dm.y = mask[n * N + m];
    dm_sh[m] = dm;
  }
  __syncthreads();

  const int v = tid & 31;        // float4 index within 128 channels
  const int slot = tid >> 5;     // 0..7

  const f4 pi4 = reinterpret_cast<const f4*>(pI)[n * (CP / 4) + v];
  const f4 wt4 = reinterpret_cast<const f4*>(Wt)[v];
  const f4* __restrict__ pJ4 = reinterpret_cast<const f4*>(pJ);
  const f4* __restrict__ rel4 = reinterpret_cast<const f4*>(relT);
  f4* __restrict__ out4 =
      reinterpret_cast<f4*>(out) + (size_t)n * N * (CP / 4);

  // d = n - m; m <= n-32 -> bin 64, m >= n+32 -> bin 0. Hoist both into regs.
  const f4 base_lo = pi4 + rel4[64 * (CP / 4) + v];   // d >= 32
  const f4 base_hi = pi4 + rel4[0 * (CP / 4) + v];    // d <= -32

#pragma unroll 4
  for (int mm = slot; mm < N; mm += 8) {
    const int d = n - mm;
    f4 base;
    if (d >= 32) {
      base = base_lo;
    } else if (d <= -32) {
      base = base_hi;
    } else {
      base = pi4 + rel4[(d + 32) * (CP / 4) + v];
    }

    const f4 pj4 = pJ4[mm * (CP / 4) + v];
    const f2 dm = dm_sh[mm];

    const f4 o = (base + pj4 + dm.x * wt4) * dm.y;
    out4[mm * (CP / 4) + v] = o;
  }
}

extern "C" void kernel_launch(void* const* d_in, const int* in_sizes, int n_in,
                              void* d_out, int out_size, void* d_ws, size_t ws_size,
                              hipStream_t stream) {
  const float* s      = (const float*)d_in[0];
  const float* trans  = (const float*)d_in[1];
  const float* p_mask = (const float*)d_in[2];
  const float* Wi     = (const float*)d_in[3];
  const float* bi     = (const float*)d_in[4];
  const float* Wj     = (const float*)d_in[5];
  const float* bj     = (const float*)d_in[6];
  const float* Wrel   = (const float*)d_in[7];
  const float* brel   = (const float*)d_in[8];
  const float* Wt     = (const float*)d_in[9];
  const float* bt     = (const float*)d_in[10];
  float* out = (float*)d_out;

  float* ws   = (float*)d_ws;
  float* pI   = ws;                 // N*CP floats
  float* pJ   = ws + N * CP;        // N*CP floats
  float* relT = ws + 2 * N * CP;    // NBIN*CP floats

  prep_kernel<<<PROJ_BLOCKS + REL_BLOCKS, 512, 0, stream>>>(
      s, Wi, bi, Wj, bj, Wrel, brel, bt, pI, pJ, relT);
  pair_kernel<<<N, 256, 0, stream>>>(
      pI, pJ, relT, Wt, trans, p_mask, out);
}